// Round 6
// baseline (34.910 us; speedup 1.0000x reference)
//
#include <hip/hip_runtime.h>
#include <math.h>

// Problem constants (match reference)
#define VOCAB   100000
#define EMBED_D 128
#define BATCH_N 16384
#define CTX     8
#define NNEG    5

#define NBLOCKS 2048
#define TPB     256                     // 4 waves/block
#define WPB     (TPB / 64)
#define NWAVES  (NBLOCKS * WPB)         // 8192 waves
#define EPW     (BATCH_N / NWAVES)      // 2 elements per wave (blocked)

// Stage 1: per-block partials of the 6 scalar contractions.
// Wave g owns elements [g*2, g*2+2), processed SEQUENTIALLY (element at a
// time) to keep live VGPRs ~50 (<=64 -> 8 waves/SIMD -> all 2048 blocks
// co-resident = 32 waves/CU). Lane i owns dims [2i, 2i+1] (float2); a wave
// gather = one contiguous 512 B row. Index loads are wave-uniform
// (readfirstlane) -> scalar s_loads, hoisted for both elements up front.
__global__ __launch_bounds__(TPB) void cbow_partial_kernel(
    const int* __restrict__ pos_u,   // [B, C]
    const int* __restrict__ pos_w,   // [B]
    const int* __restrict__ neg_w,   // [B, NEG]
    const float* __restrict__ W,     // [VOCAB, D]
    float* __restrict__ partials)    // [6][NBLOCKS]
{
    const int lane = threadIdx.x & 63;
    const int wib  = threadIdx.x >> 6;
    const int g    = blockIdx.x * WPB + wib;

    const float2* __restrict__ W2 = (const float2*)W;   // 64 float2 per row

    const int e0 = __builtin_amdgcn_readfirstlane(g * EPW);
    const int e1 = e0 + 1;

    // ---- wave-uniform index loads for BOTH elements (wide s_loads) ----
    int c0[CTX], c1[CTX];
    #pragma unroll
    for (int c = 0; c < CTX; ++c) {
        c0[c] = pos_u[e0 * CTX + c];
        c1[c] = pos_u[e1 * CTX + c];
    }
    const int ip0 = pos_w[e0];
    const int ip1 = pos_w[e1];
    int n0[NNEG], n1[NNEG];
    #pragma unroll
    for (int n = 0; n < NNEG; ++n) {
        n0[n] = neg_w[e0 * NNEG + n];
        n1[n] = neg_w[e1 * NNEG + n];
    }

    float accs[6];

    // ================= element 0: 14 gathers in flight =================
    {
        const float2 wp = W2[(size_t)ip0 * (EMBED_D / 2) + lane];
        float2 t[NNEG];
        #pragma unroll
        for (int n = 0; n < NNEG; ++n)
            t[n] = W2[(size_t)n0[n] * (EMBED_D / 2) + lane];

        float2 us = make_float2(0.f, 0.f);
        #pragma unroll
        for (int c = 0; c < CTX; ++c) {
            const float2 a = W2[(size_t)c0[c] * (EMBED_D / 2) + lane];
            us.x += a.x; us.y += a.y;
        }

        accs[0] = us.x * wp.x + us.y * wp.y;
        #pragma unroll
        for (int n = 0; n < NNEG; ++n)
            accs[1 + n] = us.x * t[n].x + us.y * t[n].y;
    }

    // ================= element 1: 14 gathers in flight =================
    {
        const float2 wp = W2[(size_t)ip1 * (EMBED_D / 2) + lane];
        float2 t[NNEG];
        #pragma unroll
        for (int n = 0; n < NNEG; ++n)
            t[n] = W2[(size_t)n1[n] * (EMBED_D / 2) + lane];

        float2 us = make_float2(0.f, 0.f);
        #pragma unroll
        for (int c = 0; c < CTX; ++c) {
            const float2 a = W2[(size_t)c1[c] * (EMBED_D / 2) + lane];
            us.x += a.x; us.y += a.y;
        }

        accs[0] += us.x * wp.x + us.y * wp.y;
        #pragma unroll
        for (int n = 0; n < NNEG; ++n)
            accs[1 + n] += us.x * t[n].x + us.y * t[n].y;
    }

    // ---- wave reduction of the 6 accumulators ----
    #pragma unroll
    for (int k = 0; k < 6; ++k) {
        float v = accs[k];
        #pragma unroll
        for (int off = 32; off > 0; off >>= 1)
            v += __shfl_down(v, off, 64);
        accs[k] = v;
    }

    __shared__ float sred[WPB][6];
    if (lane == 0) {
        #pragma unroll
        for (int k = 0; k < 6; ++k) sred[wib][k] = accs[k];
    }
    __syncthreads();

    if (threadIdx.x < 6) {
        float s = 0.f;
        #pragma unroll
        for (int w = 0; w < WPB; ++w) s += sred[w][threadIdx.x];
        partials[threadIdx.x * NBLOCKS + blockIdx.x] = s;   // [k][block]
    }
}

// Stage 2: 6 waves; wave k reduces partials[k][*] coalesced; thread 0 epilogue.
__global__ __launch_bounds__(384) void cbow_final_kernel(
    const float* __restrict__ partials, float* __restrict__ out)
{
    const int wave = threadIdx.x >> 6;   // 0..5 -> k
    const int lane = threadIdx.x & 63;

    float s = 0.f;
    for (int i = lane; i < NBLOCKS; i += 64)
        s += partials[wave * NBLOCKS + i];
    #pragma unroll
    for (int off = 32; off > 0; off >>= 1)
        s += __shfl_down(s, off, 64);

    __shared__ float sv[6];
    if (lane == 0) sv[wave] = s;
    __syncthreads();

    if (threadIdx.x == 0) {
        // log_sigmoid(x) = min(x,0) - log1p(exp(-|x|))
        const float spos = sv[0];
        float loss = -(fminf(spos, 0.f) - log1pf(expf(-fabsf(spos))));
        #pragma unroll
        for (int k = 1; k < 6; ++k) {
            const float x = -sv[k];      // log_sigmoid(-s_neg)
            loss -= (fminf(x, 0.f) - log1pf(expf(-fabsf(x))));
        }
        out[0] = loss;
    }
}

extern "C" void kernel_launch(void* const* d_in, const int* in_sizes, int n_in,
                              void* d_out, int out_size, void* d_ws, size_t ws_size,
                              hipStream_t stream) {
    const int*   pos_u = (const int*)d_in[0];
    const int*   pos_w = (const int*)d_in[1];
    const int*   neg_w = (const int*)d_in[2];
    const float* W     = (const float*)d_in[3];
    float* out = (float*)d_out;
    float* partials = (float*)d_ws;   // 6*NBLOCKS floats = 48 KB

    cbow_partial_kernel<<<NBLOCKS, TPB, 0, stream>>>(pos_u, pos_w, neg_w, W, partials);
    cbow_final_kernel<<<1, 384, 0, stream>>>(partials, out);
}